// Round 19
// baseline (557.294 us; speedup 1.0000x reference)
//
#include <hip/hip_runtime.h>

// ---------------------------------------------------------------------------
// MoE forward (top-2 of 8 experts), sparse-routed, bf16 MFMA.
// Round 19 = Round 18 + tail fusion:
//   gate weight folded into gemm1 GLU epilogue (w*(silu*h2) before bf16),
//   gemm2 scatter-adds f32 directly into out (2 commutative addends/elem,
//   zeroed out -> deterministic). pout + k_combine eliminated.
// ---------------------------------------------------------------------------

typedef __bf16 bf16x8 __attribute__((ext_vector_type(8)));
typedef float f32x4 __attribute__((ext_vector_type(4)));
typedef unsigned short us8 __attribute__((ext_vector_type(8)));

#define T_TOK 8192
#define DIMD 1024
#define NEXP 8
#define HID 2730
#define HPAD 2752
#define H2PAD 5504
#define NPAIR 16384

#define WS_CTRL  ((size_t)0)
#define WS_TOPI  ((size_t)256)
#define WS_TOPW  (WS_TOPI + 65536)
#define WS_PW    (WS_TOPW + 65536)
#define WS_PTOK  (WS_PW + 65536)
#define WS_XB    (WS_PTOK + 65536)
#define WS_W12T  (WS_XB + (size_t)16777216)
#define WS_W3T   (WS_W12T + (size_t)90177536)
#define WS_HBUF  (WS_W3T + (size_t)45088768)

#define GLOAD16(g, l) __builtin_amdgcn_global_load_lds( \
    (const __attribute__((address_space(1))) void*)(g), \
    (__attribute__((address_space(3))) void*)(l), 16, 0, 0)

__device__ __forceinline__ unsigned short f2bf(float f) {
    unsigned int u = __float_as_uint(f);
    u += 0x7fffu + ((u >> 16) & 1u);
    return (unsigned short)(u >> 16);
}

// ---------------- merged weight conversion (wide tiles, float4 reads) -------
__global__ void k_cvt_all(const float* __restrict__ w12, const float* __restrict__ w3,
                          unsigned short* __restrict__ w12t, unsigned short* __restrict__ w3t) {
    __shared__ float tile[64][129];
    int t = threadIdx.x;
    int lane16 = t & 15, rowgrp = t >> 4;
    int bid = blockIdx.x;
    if (bid < 5504) {
        int b = bid;
        int kt = b & 7; b >>= 3;
        int jt = b % 43; b /= 43;
        int half = b & 1, e = b >> 1;
        int jh0 = jt * 64, k0 = kt * 128;
        int j = jh0 + lane16 * 4;
        const float* srcb = w12 + (size_t)(e * 1024 + k0) * 5460 + half * HID + j;
        if (jh0 + 64 <= HID) {
#pragma unroll
            for (int p = 0; p < 8; ++p) {
                int kk = p * 16 + rowgrp;
                f32x4 v = *(const f32x4*)(srcb + (size_t)kk * 5460);
                tile[lane16 * 4][kk] = v[0];
                tile[lane16 * 4 + 1][kk] = v[1];
                tile[lane16 * 4 + 2][kk] = v[2];
                tile[lane16 * 4 + 3][kk] = v[3];
            }
        } else {
#pragma unroll
            for (int p = 0; p < 8; ++p) {
                int kk = p * 16 + rowgrp;
#pragma unroll
                for (int i = 0; i < 4; ++i) {
                    float v = 0.f;
                    if (j + i < HID) v = srcb[(size_t)kk * 5460 + i];
                    tile[lane16 * 4 + i][kk] = v;
                }
            }
        }
        __syncthreads();
        unsigned short* dstb = w12t + ((size_t)e * H2PAD + half * HPAD + jh0) * 1024 + k0 + lane16 * 8;
#pragma unroll
        for (int q = 0; q < 4; ++q) {
            int jl = q * 16 + rowgrp;
            us8 v;
#pragma unroll
            for (int b8 = 0; b8 < 8; ++b8) v[b8] = f2bf(tile[jl][lane16 * 8 + b8]);
            *(us8*)(dstb + (size_t)jl * 1024) = v;
        }
    } else {
        int b2 = bid - 5504;
        int kt = b2 % 22; b2 /= 22;
        int dt = b2 & 15, e = b2 >> 4;
        int d0 = dt * 64, k0 = kt * 128;
        int d = d0 + lane16 * 4;
        const float* srcb = w3 + (size_t)(e * HID) * 1024 + d;
#pragma unroll
        for (int p = 0; p < 8; ++p) {
            int kk = k0 + p * 16 + rowgrp;
            f32x4 v = {0.f, 0.f, 0.f, 0.f};
            if (kk < HID) v = *(const f32x4*)(srcb + (size_t)kk * 1024);
            tile[lane16 * 4][p * 16 + rowgrp] = v[0];
            tile[lane16 * 4 + 1][p * 16 + rowgrp] = v[1];
            tile[lane16 * 4 + 2][p * 16 + rowgrp] = v[2];
            tile[lane16 * 4 + 3][p * 16 + rowgrp] = v[3];
        }
        __syncthreads();
        if (k0 + lane16 * 8 + 8 <= HPAD) {
            unsigned short* dstb = w3t + ((size_t)e * 1024 + d0) * HPAD + k0 + lane16 * 8;
#pragma unroll
            for (int q = 0; q < 4; ++q) {
                int dl = q * 16 + rowgrp;
                us8 v;
#pragma unroll
                for (int b8 = 0; b8 < 8; ++b8) v[b8] = f2bf(tile[dl][lane16 * 8 + b8]);
                *(us8*)(dstb + (size_t)dl * HPAD) = v;
            }
        }
    }
}

// ---------------- router (fused x->bf16): fp64 logits, stable top-2 ---------
__global__ void k_router(const float4* __restrict__ x4, const float* __restrict__ wr,
                         ushort4* __restrict__ xb4,
                         int* __restrict__ topi, float* __restrict__ topw) {
    int wid = threadIdx.x >> 6, lane = threadIdx.x & 63;
    int t = blockIdx.x * 4 + wid;
    const float4* xr = x4 + (size_t)t * 256;
    double acc[NEXP];
#pragma unroll
    for (int e = 0; e < NEXP; ++e) acc[e] = 0.0;
#pragma unroll
    for (int it = 0; it < 4; ++it) {
        int d4 = it * 64 + lane;
        float4 v = xr[d4];
        ushort4 r;
        r.x = f2bf(v.x); r.y = f2bf(v.y); r.z = f2bf(v.z); r.w = f2bf(v.w);
        xb4[(size_t)t * 256 + d4] = r;
        const float* w = wr + (size_t)d4 * 4 * NEXP;
#pragma unroll
        for (int e = 0; e < NEXP; ++e) {
            acc[e] += (double)v.x * (double)w[e]
                    + (double)v.y * (double)w[NEXP + e]
                    + (double)v.z * (double)w[2 * NEXP + e]
                    + (double)v.w * (double)w[3 * NEXP + e];
        }
    }
#pragma unroll
    for (int e = 0; e < NEXP; ++e) {
        for (int off = 32; off > 0; off >>= 1) acc[e] += __shfl_down(acc[e], off);
    }
    if (lane == 0) {
        double b0 = -1e300, b1 = -1e300; int i0 = 0, i1 = 0;
#pragma unroll
        for (int e = 0; e < NEXP; ++e) {
            double v = acc[e];
            if (v > b0) { b1 = b0; i1 = i0; b0 = v; i0 = e; }
            else if (v > b1) { b1 = v; i1 = e; }
        }
        float e1 = expf((float)(b1 - b0));
        float w0 = 1.0f / (1.0f + e1);
        float w1 = e1 / (1.0f + e1);
        topi[2 * t] = i0; topi[2 * t + 1] = i1;
        topw[2 * t] = w0; topw[2 * t + 1] = w1;
    }
}

// ---------------- pack: counts + scan + stable compact, one block -----------
// Emits per-pair gate weight pw[p] for gemm1's fused epilogue.
__global__ __launch_bounds__(1024) void k_pack(const int* __restrict__ topi,
                                               const float* __restrict__ topw,
                                               int* __restrict__ ctrl,
                                               int* __restrict__ ptok,
                                               float* __restrict__ pw) {
    __shared__ int scnt[NEXP][1024];
    __shared__ int offs[NEXP];
    int tid = threadIdx.x;
    int lc[NEXP];
#pragma unroll
    for (int e = 0; e < NEXP; ++e) lc[e] = 0;
    int t0 = tid * 8;
#pragma unroll
    for (int i = 0; i < 8; ++i) {
        int t = t0 + i;
        lc[topi[2 * t]]++;
        lc[topi[2 * t + 1]]++;
    }
#pragma unroll
    for (int e = 0; e < NEXP; ++e) scnt[e][tid] = lc[e];
    __syncthreads();
    for (int off = 1; off < 1024; off <<= 1) {
        int v[NEXP];
#pragma unroll
        for (int e = 0; e < NEXP; ++e) v[e] = (tid >= off) ? scnt[e][tid - off] : 0;
        __syncthreads();
#pragma unroll
        for (int e = 0; e < NEXP; ++e) scnt[e][tid] += v[e];
        __syncthreads();
    }
    if (tid == 0) {
        int s = 0;
#pragma unroll
        for (int e = 0; e < NEXP; ++e) {
            int c = scnt[e][1023];
            ctrl[e] = c;
            ctrl[16 + e] = s;
            offs[e] = s;
            s += c;
        }
        ctrl[16 + NEXP] = s;
    }
    __syncthreads();
    int r[NEXP];
#pragma unroll
    for (int e = 0; e < NEXP; ++e) r[e] = offs[e] + scnt[e][tid] - lc[e];
#pragma unroll
    for (int i = 0; i < 8; ++i) {
        int t = t0 + i;
#pragma unroll
        for (int k = 0; k < 2; ++k) {
            int e = topi[2 * t + k];
            int p = r[e]++;
            ptok[p] = t;
            pw[p] = topw[2 * t + k];
        }
    }
}

// ---------------- GEMM1 + GLU + gate: h = w * silu(x@W1)*(x@W2) -------------
// BM=256 x BN=128(64j x 2 halves), BK=32, 512 thr, 8 waves (4M x 2N).
// Tri-buffer (compile-time slots via unroll-by-3), 1 barrier/K-step, vmcnt(3).
#define G1_STAGE(S) do { \
    GLOAD16(aSrc0, ALp + (S) * 8192 + wid * 512); aSrc0 += 64; \
    GLOAD16(aSrc1, ALp + (S) * 8192 + 4096 + wid * 512); aSrc1 += 64; \
    GLOAD16(bSrc, BLp + (S) * 4096 + wid * 512); bSrc += 64; \
} while (0)

#define G1_STEP(CUR, STG, WAITSTR, DOSTAGE) do { \
    asm volatile("s_waitcnt " WAITSTR ::: "memory"); \
    __builtin_amdgcn_s_barrier(); \
    if (DOSTAGE) G1_STAGE(STG); \
    const unsigned short* Ab = ALp + (CUR) * 8192 + cSwz; \
    const unsigned short* Bb = BLp + (CUR) * 4096 + cSwz; \
    bf16x8 af[4], bfr[2][2]; \
    _Pragma("unroll") \
    for (int m = 0; m < 4; ++m) af[m] = *(const bf16x8*)(Ab + aoff[m]); \
    _Pragma("unroll") \
    for (int h = 0; h < 2; ++h) \
        _Pragma("unroll") \
        for (int n = 0; n < 2; ++n) bfr[h][n] = *(const bf16x8*)(Bb + boff[h][n]); \
    __builtin_amdgcn_s_setprio(1); \
    _Pragma("unroll") \
    for (int h = 0; h < 2; ++h) \
        _Pragma("unroll") \
        for (int m = 0; m < 4; ++m) \
            _Pragma("unroll") \
            for (int n = 0; n < 2; ++n) \
                acc[m][h][n] = __builtin_amdgcn_mfma_f32_16x16x32_bf16( \
                    af[m], bfr[h][n], acc[m][h][n], 0, 0, 0); \
    __builtin_amdgcn_s_setprio(0); \
} while (0)

__global__ __launch_bounds__(512, 4) void k_gemm1(
    const unsigned short* __restrict__ xb,
    const unsigned short* __restrict__ w12t,
    const int* __restrict__ ctrl,
    const int* __restrict__ ptok,
    const float* __restrict__ pw,
    unsigned short* __restrict__ hbuf) {
    int e = blockIdx.z;
    int n_e = ctrl[e];
    int r0 = blockIdx.y * 256;
    if (r0 >= n_e) return;
    int p0 = ctrl[16 + e] + r0;
    int j0 = blockIdx.x * 64;

    __shared__ unsigned short AL[3][256][32];   // 48 KB
    __shared__ unsigned short BL[3][128][32];   // 24 KB

    int tid = threadIdx.x, lane = tid & 63, wid = tid >> 6;
    int wm = wid >> 1, wn = wid & 1;            // 4M x 2N
    int lr = lane & 15, lk = lane >> 4;

    unsigned short* ALp = &AL[0][0][0];
    unsigned short* BLp = &BL[0][0][0];

    int swzB = (((tid & 3) ^ ((tid >> 3) & 3)) << 4);
    const char* aSrc0;
    const char* aSrc1;
    {
        int row0 = (tid >> 2);
        int row1 = 128 + (tid >> 2);
        int tok0 = (r0 + row0 < n_e) ? ptok[p0 + row0] : ptok[p0];
        int tok1 = (r0 + row1 < n_e) ? ptok[p0 + row1] : ptok[p0];
        aSrc0 = (const char*)(xb + (size_t)tok0 * 1024) + swzB;
        aSrc1 = (const char*)(xb + (size_t)tok1 * 1024) + swzB;
    }
    const char* bSrc;
    {
        int r = tid >> 2;                       // 0..127: half*64 + jj
        int half = r >> 6, jj = r & 63;
        bSrc = (const char*)(w12t + ((size_t)e * H2PAD + half * HPAD + j0 + jj) * 1024) + swzB;
    }

    f32x4 acc[4][2][2];
#pragma unroll
    for (int m = 0; m < 4; ++m)
#pragma unroll
        for (int h = 0; h < 2; ++h)
#pragma unroll
            for (int n = 0; n < 2; ++n) acc[m][h][n] = (f32x4){0.f, 0.f, 0.f, 0.f};

    int cSwz = ((lk ^ ((lr >> 1) & 3)) << 3);
    int aoff[4], boff[2][2];
#pragma unroll
    for (int m = 0; m < 4; ++m) aoff[m] = (wm * 64 + m * 16 + lr) * 32;
#pragma unroll
    for (int h = 0; h < 2; ++h)
#pragma unroll
        for (int n = 0; n < 2; ++n) boff[h][n] = (h * 64 + wn * 32 + n * 16 + lr) * 32;

    G1_STAGE(0);
    G1_STAGE(1);

#pragma unroll 1
    for (int t3 = 0; t3 < 10; ++t3) {
        G1_STEP(0, 2, "vmcnt(3)", true);
        G1_STEP(1, 0, "vmcnt(3)", true);
        G1_STEP(2, 1, "vmcnt(3)", true);
    }
    G1_STEP(0, 2, "vmcnt(3)", false);
    G1_STEP(1, 0, "vmcnt(0)", false);

#pragma unroll
    for (int m = 0; m < 4; ++m)
#pragma unroll
        for (int q = 0; q < 4; ++q) {
            int rl = wm * 64 + m * 16 + lk * 4 + q;
            if (r0 + rl < n_e) {
                float w = pw[p0 + rl];
#pragma unroll
                for (int n = 0; n < 2; ++n) {
                    float v1 = acc[m][0][n][q];
                    float v2 = acc[m][1][n][q];
                    float hv = w * (v1 * (1.0f / (1.0f + __expf(-v1))) * v2);
                    hbuf[(size_t)(p0 + rl) * HPAD + (j0 + wn * 32 + n * 16 + lr)] = f2bf(hv);
                }
            }
        }
}

// ---------------- GEMM2 + scatter-add: out[tok] += h_scaled @ W3 ------------
// BM=256 x BN=128 d, BK=32, 512 thr, 8 waves (4M x 2N), NT=86, tri-buffer.
// Epilogue: f32 atomicAdd into out — 2 commutative addends/elem, zeroed out.
#define G2_STEP(CUR, STG, WAITSTR, DOSTAGE) do { \
    asm volatile("s_waitcnt " WAITSTR ::: "memory"); \
    __builtin_amdgcn_s_barrier(); \
    if (DOSTAGE) G1_STAGE(STG); \
    const unsigned short* Ab = ALp + (CUR) * 8192 + cSwz; \
    const unsigned short* Bb = BLp + (CUR) * 4096 + cSwz; \
    bf16x8 af[4], bfr[4]; \
    _Pragma("unroll") \
    for (int m = 0; m < 4; ++m) af[m] = *(const bf16x8*)(Ab + aoff[m]); \
    _Pragma("unroll") \
    for (int n = 0; n < 4; ++n) bfr[n] = *(const bf16x8*)(Bb + boff[n]); \
    __builtin_amdgcn_s_setprio(1); \
    _Pragma("unroll") \
    for (int m = 0; m < 4; ++m) \
        _Pragma("unroll") \
        for (int n = 0; n < 4; ++n) \
            acc[m][n] = __builtin_amdgcn_mfma_f32_16x16x32_bf16( \
                af[m], bfr[n], acc[m][n], 0, 0, 0); \
    __builtin_amdgcn_s_setprio(0); \
} while (0)

__global__ __launch_bounds__(512, 4) void k_gemm2(
    const unsigned short* __restrict__ hbuf,
    const unsigned short* __restrict__ w3t,
    const int* __restrict__ ctrl,
    const int* __restrict__ ptok,
    float* __restrict__ out) {
    int e = blockIdx.z;
    int n_e = ctrl[e];
    int r0 = blockIdx.y * 256;
    if (r0 >= n_e) return;
    int p0 = ctrl[16 + e] + r0;
    int d0 = blockIdx.x * 128;

    __shared__ unsigned short AL[3][256][32];
    __shared__ unsigned short BL[3][128][32];

    int tid = threadIdx.x, lane = tid & 63, wid = tid >> 6;
    int wm = wid >> 1, wn = wid & 1;
    int lr = lane & 15, lk = lane >> 4;

    unsigned short* ALp = &AL[0][0][0];
    unsigned short* BLp = &BL[0][0][0];

    int swzB = (((tid & 3) ^ ((tid >> 3) & 3)) << 4);
    const char* aSrc0;
    const char* aSrc1;
    {
        int row0 = (tid >> 2);
        int row1 = 128 + (tid >> 2);
        int arr0 = (r0 + row0 < n_e) ? row0 : 0;
        int arr1 = (r0 + row1 < n_e) ? row1 : 0;
        aSrc0 = (const char*)(hbuf + (size_t)(p0 + arr0) * HPAD) + swzB;
        aSrc1 = (const char*)(hbuf + (size_t)(p0 + arr1) * HPAD) + swzB;
    }
    const char* bSrc = (const char*)(w3t + ((size_t)e * 1024 + d0 + (tid >> 2)) * HPAD) + swzB;

    f32x4 acc[4][4];
#pragma unroll
    for (int m = 0; m < 4; ++m)
#pragma unroll
        for (int n = 0; n < 4; ++n) acc[m][n] = (f32x4){0.f, 0.f, 0.f, 0.f};

    int cSwz = ((lk ^ ((lr >> 1) & 3)) << 3);
    int aoff[4], boff[4];
#pragma unroll
    for (int m = 0; m < 4; ++m) aoff[m] = (wm * 64 + m * 16 + lr) * 32;
#pragma unroll
    for (int n = 0; n < 4; ++n) boff[n] = (wn * 64 + n * 16 + lr) * 32;

    G1_STAGE(0);
    G1_STAGE(1);

#pragma unroll 1
    for (int t3 = 0; t3 < 28; ++t3) {
        G2_STEP(0, 2, "vmcnt(3)", true);
        G2_STEP(1, 0, "vmcnt(3)", true);
        G2_STEP(2, 1, "vmcnt(3)", true);
    }
    G2_STEP(0, 2, "vmcnt(3)", false);
    G2_STEP(1, 0, "vmcnt(0)", false);

#pragma unroll
    for (int m = 0; m < 4; ++m) {
        int rl0 = wm * 64 + m * 16 + lk * 4;
#pragma unroll
        for (int q = 0; q < 4; ++q) {
            int rl = rl0 + q;
            if (r0 + rl < n_e) {
                int tok = ptok[p0 + rl];
                float* orow = out + (size_t)tok * DIMD + d0;
#pragma unroll
                for (int n = 0; n < 4; ++n) {
                    atomicAdd(orow + (wn * 64 + n * 16 + lr), acc[m][n][q]);
                }
            }
        }
    }
}

extern "C" void kernel_launch(void* const* d_in, const int* in_sizes, int n_in,
                              void* d_out, int out_size, void* d_ws, size_t ws_size,
                              hipStream_t stream) {
    const float* x   = (const float*)d_in[0];
    const float* wr  = (const float*)d_in[1];
    const float* w12 = (const float*)d_in[2];
    const float* w3  = (const float*)d_in[3];
    float* out = (float*)d_out;

    char* ws = (char*)d_ws;
    int*            ctrl = (int*)(ws + WS_CTRL);
    int*            topi = (int*)(ws + WS_TOPI);
    float*          topw = (float*)(ws + WS_TOPW);
    float*          pw   = (float*)(ws + WS_PW);
    int*            ptok = (int*)(ws + WS_PTOK);
    unsigned short* xb   = (unsigned short*)(ws + WS_XB);
    unsigned short* w12t = (unsigned short*)(ws + WS_W12T);
    unsigned short* w3t  = (unsigned short*)(ws + WS_W3T);
    unsigned short* hbuf = (unsigned short*)(ws + WS_HBUF);

    (void)ws_size; (void)in_sizes; (void)n_in; (void)out_size;

    (void)hipMemsetAsync(out, 0, (size_t)T_TOK * DIMD * sizeof(float), stream);
    k_cvt_all<<<8320, 256, 0, stream>>>(w12, w3, w12t, w3t);
    k_router<<<2048, 256, 0, stream>>>((const float4*)x, wr, (ushort4*)xb, topi, topw);
    k_pack<<<1, 1024, 0, stream>>>(topi, topw, ctrl, ptok, pw);
    k_gemm1<<<dim3(43, 32, 8), 512, 0, stream>>>(xb, w12t, ctrl, ptok, pw, hbuf);
    k_gemm2<<<dim3(8, 32, 8), 512, 0, stream>>>(hbuf, w3t, ctrl, ptok, out);
}

// Round 20
// 542.137 us; speedup vs baseline: 1.0280x; 1.0280x over previous
//
#include <hip/hip_runtime.h>

// ---------------------------------------------------------------------------
// MoE forward (top-2 of 8 experts), sparse-routed, bf16 MFMA.
// Round 20 = exact revert to Round 18 (best verified: 542us).
//   R19's atomic-scatter tail fusion regressed (+15us): gemm2 atomics cost
//   ~50us > 35us saved by deleting combine. Plain stores + combine wins.
// Final structure: cvt(wide-tile) -> router(fused x->bf16, fp64 top-2) ->
//   pack(1-block scan) -> gemm1(256x128 BK32 tri-buf, unroll-3 const slots,
//   gload_lds+swizzle, 0 conflicts, 791 TF) -> gemm2(same engine, K=2752)
//   -> combine.
// ---------------------------------------------------------------------------

typedef __bf16 bf16x8 __attribute__((ext_vector_type(8)));
typedef float f32x4 __attribute__((ext_vector_type(4)));
typedef unsigned short us8 __attribute__((ext_vector_type(8)));

#define T_TOK 8192
#define DIMD 1024
#define NEXP 8
#define HID 2730
#define HPAD 2752
#define H2PAD 5504
#define NPAIR 16384

#define WS_CTRL  ((size_t)0)
#define WS_TOPI  ((size_t)256)
#define WS_TOPW  (WS_TOPI + 65536)
#define WS_POS   (WS_TOPW + 65536)
#define WS_PTOK  (WS_POS + 65536)
#define WS_XB    (WS_PTOK + 65536)
#define WS_W12T  (WS_XB + (size_t)16777216)
#define WS_W3T   (WS_W12T + (size_t)90177536)
#define WS_HBUF  (WS_W3T + (size_t)45088768)
#define WS_POUT  (WS_HBUF + (size_t)90177536)

#define GLOAD16(g, l) __builtin_amdgcn_global_load_lds( \
    (const __attribute__((address_space(1))) void*)(g), \
    (__attribute__((address_space(3))) void*)(l), 16, 0, 0)

__device__ __forceinline__ unsigned short f2bf(float f) {
    unsigned int u = __float_as_uint(f);
    u += 0x7fffu + ((u >> 16) & 1u);
    return (unsigned short)(u >> 16);
}

// ---------------- merged weight conversion (wide tiles, float4 reads) -------
__global__ void k_cvt_all(const float* __restrict__ w12, const float* __restrict__ w3,
                          unsigned short* __restrict__ w12t, unsigned short* __restrict__ w3t) {
    __shared__ float tile[64][129];
    int t = threadIdx.x;
    int lane16 = t & 15, rowgrp = t >> 4;
    int bid = blockIdx.x;
    if (bid < 5504) {
        int b = bid;
        int kt = b & 7; b >>= 3;
        int jt = b % 43; b /= 43;
        int half = b & 1, e = b >> 1;
        int jh0 = jt * 64, k0 = kt * 128;
        int j = jh0 + lane16 * 4;
        const float* srcb = w12 + (size_t)(e * 1024 + k0) * 5460 + half * HID + j;
        if (jh0 + 64 <= HID) {
#pragma unroll
            for (int p = 0; p < 8; ++p) {
                int kk = p * 16 + rowgrp;
                f32x4 v = *(const f32x4*)(srcb + (size_t)kk * 5460);
                tile[lane16 * 4][kk] = v[0];
                tile[lane16 * 4 + 1][kk] = v[1];
                tile[lane16 * 4 + 2][kk] = v[2];
                tile[lane16 * 4 + 3][kk] = v[3];
            }
        } else {
#pragma unroll
            for (int p = 0; p < 8; ++p) {
                int kk = p * 16 + rowgrp;
#pragma unroll
                for (int i = 0; i < 4; ++i) {
                    float v = 0.f;
                    if (j + i < HID) v = srcb[(size_t)kk * 5460 + i];
                    tile[lane16 * 4 + i][kk] = v;
                }
            }
        }
        __syncthreads();
        unsigned short* dstb = w12t + ((size_t)e * H2PAD + half * HPAD + jh0) * 1024 + k0 + lane16 * 8;
#pragma unroll
        for (int q = 0; q < 4; ++q) {
            int jl = q * 16 + rowgrp;
            us8 v;
#pragma unroll
            for (int b8 = 0; b8 < 8; ++b8) v[b8] = f2bf(tile[jl][lane16 * 8 + b8]);
            *(us8*)(dstb + (size_t)jl * 1024) = v;
        }
    } else {
        int b2 = bid - 5504;
        int kt = b2 % 22; b2 /= 22;
        int dt = b2 & 15, e = b2 >> 4;
        int d0 = dt * 64, k0 = kt * 128;
        int d = d0 + lane16 * 4;
        const float* srcb = w3 + (size_t)(e * HID) * 1024 + d;
#pragma unroll
        for (int p = 0; p < 8; ++p) {
            int kk = k0 + p * 16 + rowgrp;
            f32x4 v = {0.f, 0.f, 0.f, 0.f};
            if (kk < HID) v = *(const f32x4*)(srcb + (size_t)kk * 1024);
            tile[lane16 * 4][p * 16 + rowgrp] = v[0];
            tile[lane16 * 4 + 1][p * 16 + rowgrp] = v[1];
            tile[lane16 * 4 + 2][p * 16 + rowgrp] = v[2];
            tile[lane16 * 4 + 3][p * 16 + rowgrp] = v[3];
        }
        __syncthreads();
        if (k0 + lane16 * 8 + 8 <= HPAD) {
            unsigned short* dstb = w3t + ((size_t)e * 1024 + d0) * HPAD + k0 + lane16 * 8;
#pragma unroll
            for (int q = 0; q < 4; ++q) {
                int dl = q * 16 + rowgrp;
                us8 v;
#pragma unroll
                for (int b8 = 0; b8 < 8; ++b8) v[b8] = f2bf(tile[dl][lane16 * 8 + b8]);
                *(us8*)(dstb + (size_t)dl * HPAD) = v;
            }
        }
    }
}

// ---------------- router (fused x->bf16): fp64 logits, stable top-2 ---------
__global__ void k_router(const float4* __restrict__ x4, const float* __restrict__ wr,
                         ushort4* __restrict__ xb4,
                         int* __restrict__ topi, float* __restrict__ topw) {
    int wid = threadIdx.x >> 6, lane = threadIdx.x & 63;
    int t = blockIdx.x * 4 + wid;
    const float4* xr = x4 + (size_t)t * 256;
    double acc[NEXP];
#pragma unroll
    for (int e = 0; e < NEXP; ++e) acc[e] = 0.0;
#pragma unroll
    for (int it = 0; it < 4; ++it) {
        int d4 = it * 64 + lane;
        float4 v = xr[d4];
        ushort4 r;
        r.x = f2bf(v.x); r.y = f2bf(v.y); r.z = f2bf(v.z); r.w = f2bf(v.w);
        xb4[(size_t)t * 256 + d4] = r;
        const float* w = wr + (size_t)d4 * 4 * NEXP;
#pragma unroll
        for (int e = 0; e < NEXP; ++e) {
            acc[e] += (double)v.x * (double)w[e]
                    + (double)v.y * (double)w[NEXP + e]
                    + (double)v.z * (double)w[2 * NEXP + e]
                    + (double)v.w * (double)w[3 * NEXP + e];
        }
    }
#pragma unroll
    for (int e = 0; e < NEXP; ++e) {
        for (int off = 32; off > 0; off >>= 1) acc[e] += __shfl_down(acc[e], off);
    }
    if (lane == 0) {
        double b0 = -1e300, b1 = -1e300; int i0 = 0, i1 = 0;
#pragma unroll
        for (int e = 0; e < NEXP; ++e) {
            double v = acc[e];
            if (v > b0) { b1 = b0; i1 = i0; b0 = v; i0 = e; }
            else if (v > b1) { b1 = v; i1 = e; }
        }
        float e1 = expf((float)(b1 - b0));
        float w0 = 1.0f / (1.0f + e1);
        float w1 = e1 / (1.0f + e1);
        topi[2 * t] = i0; topi[2 * t + 1] = i1;
        topw[2 * t] = w0; topw[2 * t + 1] = w1;
    }
}

// ---------------- pack: counts + scan + stable compact, one block -----------
__global__ __launch_bounds__(1024) void k_pack(const int* __restrict__ topi,
                                               int* __restrict__ ctrl,
                                               int* __restrict__ ptok,
                                               int* __restrict__ pos) {
    __shared__ int scnt[NEXP][1024];
    __shared__ int offs[NEXP];
    int tid = threadIdx.x;
    int lc[NEXP];
#pragma unroll
    for (int e = 0; e < NEXP; ++e) lc[e] = 0;
    int t0 = tid * 8;
#pragma unroll
    for (int i = 0; i < 8; ++i) {
        int t = t0 + i;
        lc[topi[2 * t]]++;
        lc[topi[2 * t + 1]]++;
    }
#pragma unroll
    for (int e = 0; e < NEXP; ++e) scnt[e][tid] = lc[e];
    __syncthreads();
    for (int off = 1; off < 1024; off <<= 1) {
        int v[NEXP];
#pragma unroll
        for (int e = 0; e < NEXP; ++e) v[e] = (tid >= off) ? scnt[e][tid - off] : 0;
        __syncthreads();
#pragma unroll
        for (int e = 0; e < NEXP; ++e) scnt[e][tid] += v[e];
        __syncthreads();
    }
    if (tid == 0) {
        int s = 0;
#pragma unroll
        for (int e = 0; e < NEXP; ++e) {
            int c = scnt[e][1023];
            ctrl[e] = c;
            ctrl[16 + e] = s;
            offs[e] = s;
            s += c;
        }
        ctrl[16 + NEXP] = s;
    }
    __syncthreads();
    int r[NEXP];
#pragma unroll
    for (int e = 0; e < NEXP; ++e) r[e] = offs[e] + scnt[e][tid] - lc[e];
#pragma unroll
    for (int i = 0; i < 8; ++i) {
        int t = t0 + i;
#pragma unroll
        for (int k = 0; k < 2; ++k) {
            int e = topi[2 * t + k];
            int p = r[e]++;
            ptok[p] = t;
            pos[2 * t + k] = p;
        }
    }
}

// ---------------- GEMM1 + GLU: h = silu(x@W1)*(x@W2), bf16 out --------------
// BM=256 x BN=128(64j x 2 halves), BK=32, 512 thr, 8 waves (4M x 2N).
// Tri-buffer (compile-time slots via unroll-by-3), 1 barrier/K-step, vmcnt(3).
#define G1_STAGE(S) do { \
    GLOAD16(aSrc0, ALp + (S) * 8192 + wid * 512); aSrc0 += 64; \
    GLOAD16(aSrc1, ALp + (S) * 8192 + 4096 + wid * 512); aSrc1 += 64; \
    GLOAD16(bSrc, BLp + (S) * 4096 + wid * 512); bSrc += 64; \
} while (0)

#define G1_STEP(CUR, STG, WAITSTR, DOSTAGE) do { \
    asm volatile("s_waitcnt " WAITSTR ::: "memory"); \
    __builtin_amdgcn_s_barrier(); \
    if (DOSTAGE) G1_STAGE(STG); \
    const unsigned short* Ab = ALp + (CUR) * 8192 + cSwz; \
    const unsigned short* Bb = BLp + (CUR) * 4096 + cSwz; \
    bf16x8 af[4], bfr[2][2]; \
    _Pragma("unroll") \
    for (int m = 0; m < 4; ++m) af[m] = *(const bf16x8*)(Ab + aoff[m]); \
    _Pragma("unroll") \
    for (int h = 0; h < 2; ++h) \
        _Pragma("unroll") \
        for (int n = 0; n < 2; ++n) bfr[h][n] = *(const bf16x8*)(Bb + boff[h][n]); \
    __builtin_amdgcn_s_setprio(1); \
    _Pragma("unroll") \
    for (int h = 0; h < 2; ++h) \
        _Pragma("unroll") \
        for (int m = 0; m < 4; ++m) \
            _Pragma("unroll") \
            for (int n = 0; n < 2; ++n) \
                acc[m][h][n] = __builtin_amdgcn_mfma_f32_16x16x32_bf16( \
                    af[m], bfr[h][n], acc[m][h][n], 0, 0, 0); \
    __builtin_amdgcn_s_setprio(0); \
} while (0)

__global__ __launch_bounds__(512, 4) void k_gemm1(
    const unsigned short* __restrict__ xb,
    const unsigned short* __restrict__ w12t,
    const int* __restrict__ ctrl,
    const int* __restrict__ ptok,
    unsigned short* __restrict__ hbuf) {
    int e = blockIdx.z;
    int n_e = ctrl[e];
    int r0 = blockIdx.y * 256;
    if (r0 >= n_e) return;
    int p0 = ctrl[16 + e] + r0;
    int j0 = blockIdx.x * 64;

    __shared__ unsigned short AL[3][256][32];   // 48 KB
    __shared__ unsigned short BL[3][128][32];   // 24 KB

    int tid = threadIdx.x, lane = tid & 63, wid = tid >> 6;
    int wm = wid >> 1, wn = wid & 1;            // 4M x 2N
    int lr = lane & 15, lk = lane >> 4;

    unsigned short* ALp = &AL[0][0][0];
    unsigned short* BLp = &BL[0][0][0];

    int swzB = (((tid & 3) ^ ((tid >> 3) & 3)) << 4);
    const char* aSrc0;
    const char* aSrc1;
    {
        int row0 = (tid >> 2);
        int row1 = 128 + (tid >> 2);
        int tok0 = (r0 + row0 < n_e) ? ptok[p0 + row0] : ptok[p0];
        int tok1 = (r0 + row1 < n_e) ? ptok[p0 + row1] : ptok[p0];
        aSrc0 = (const char*)(xb + (size_t)tok0 * 1024) + swzB;
        aSrc1 = (const char*)(xb + (size_t)tok1 * 1024) + swzB;
    }
    const char* bSrc;
    {
        int r = tid >> 2;                       // 0..127: half*64 + jj
        int half = r >> 6, jj = r & 63;
        bSrc = (const char*)(w12t + ((size_t)e * H2PAD + half * HPAD + j0 + jj) * 1024) + swzB;
    }

    f32x4 acc[4][2][2];
#pragma unroll
    for (int m = 0; m < 4; ++m)
#pragma unroll
        for (int h = 0; h < 2; ++h)
#pragma unroll
            for (int n = 0; n < 2; ++n) acc[m][h][n] = (f32x4){0.f, 0.f, 0.f, 0.f};

    // loop-invariant per-lane fragment offsets (ushort units)
    int cSwz = ((lk ^ ((lr >> 1) & 3)) << 3);
    int aoff[4], boff[2][2];
#pragma unroll
    for (int m = 0; m < 4; ++m) aoff[m] = (wm * 64 + m * 16 + lr) * 32;
#pragma unroll
    for (int h = 0; h < 2; ++h)
#pragma unroll
        for (int n = 0; n < 2; ++n) boff[h][n] = (h * 64 + wn * 32 + n * 16 + lr) * 32;

    G1_STAGE(0);
    G1_STAGE(1);

#pragma unroll 1
    for (int t3 = 0; t3 < 10; ++t3) {
        G1_STEP(0, 2, "vmcnt(3)", true);
        G1_STEP(1, 0, "vmcnt(3)", true);
        G1_STEP(2, 1, "vmcnt(3)", true);
    }
    G1_STEP(0, 2, "vmcnt(3)", false);
    G1_STEP(1, 0, "vmcnt(0)", false);

#pragma unroll
    for (int m = 0; m < 4; ++m)
#pragma unroll
        for (int n = 0; n < 2; ++n)
#pragma unroll
            for (int q = 0; q < 4; ++q) {
                int rl = wm * 64 + m * 16 + lk * 4 + q;
                if (r0 + rl < n_e) {
                    float v1 = acc[m][0][n][q];
                    float v2 = acc[m][1][n][q];
                    float hv = v1 * (1.0f / (1.0f + __expf(-v1))) * v2;
                    hbuf[(size_t)(p0 + rl) * HPAD + (j0 + wn * 32 + n * 16 + lr)] = f2bf(hv);
                }
            }
}

// ---------------- GEMM2: pout[p] = h[p] @ W3  (plain coalesced stores) ------
// BM=256 x BN=128 d, BK=32, 512 thr, 8 waves (4M x 2N), NT=86, tri-buffer
// with compile-time slots (86 = 3*28 + 2).
#define G2_STEP(CUR, STG, WAITSTR, DOSTAGE) do { \
    asm volatile("s_waitcnt " WAITSTR ::: "memory"); \
    __builtin_amdgcn_s_barrier(); \
    if (DOSTAGE) G1_STAGE(STG); \
    const unsigned short* Ab = ALp + (CUR) * 8192 + cSwz; \
    const unsigned short* Bb = BLp + (CUR) * 4096 + cSwz; \
    bf16x8 af[4], bfr[4]; \
    _Pragma("unroll") \
    for (int m = 0; m < 4; ++m) af[m] = *(const bf16x8*)(Ab + aoff[m]); \
    _Pragma("unroll") \
    for (int n = 0; n < 4; ++n) bfr[n] = *(const bf16x8*)(Bb + boff[n]); \
    __builtin_amdgcn_s_setprio(1); \
    _Pragma("unroll") \
    for (int m = 0; m < 4; ++m) \
        _Pragma("unroll") \
        for (int n = 0; n < 4; ++n) \
            acc[m][n] = __builtin_amdgcn_mfma_f32_16x16x32_bf16( \
                af[m], bfr[n], acc[m][n], 0, 0, 0); \
    __builtin_amdgcn_s_setprio(0); \
} while (0)

__global__ __launch_bounds__(512, 4) void k_gemm2(
    const unsigned short* __restrict__ hbuf,
    const unsigned short* __restrict__ w3t,
    const int* __restrict__ ctrl,
    float* __restrict__ pout) {
    int e = blockIdx.z;
    int n_e = ctrl[e];
    int r0 = blockIdx.y * 256;
    if (r0 >= n_e) return;
    int p0 = ctrl[16 + e] + r0;
    int d0 = blockIdx.x * 128;

    __shared__ unsigned short AL[3][256][32];
    __shared__ unsigned short BL[3][128][32];

    int tid = threadIdx.x, lane = tid & 63, wid = tid >> 6;
    int wm = wid >> 1, wn = wid & 1;
    int lr = lane & 15, lk = lane >> 4;

    unsigned short* ALp = &AL[0][0][0];
    unsigned short* BLp = &BL[0][0][0];

    int swzB = (((tid & 3) ^ ((tid >> 3) & 3)) << 4);
    const char* aSrc0;
    const char* aSrc1;
    {
        int row0 = (tid >> 2);
        int row1 = 128 + (tid >> 2);
        int arr0 = (r0 + row0 < n_e) ? row0 : 0;
        int arr1 = (r0 + row1 < n_e) ? row1 : 0;
        aSrc0 = (const char*)(hbuf + (size_t)(p0 + arr0) * HPAD) + swzB;
        aSrc1 = (const char*)(hbuf + (size_t)(p0 + arr1) * HPAD) + swzB;
    }
    const char* bSrc = (const char*)(w3t + ((size_t)e * 1024 + d0 + (tid >> 2)) * HPAD) + swzB;

    f32x4 acc[4][4];
#pragma unroll
    for (int m = 0; m < 4; ++m)
#pragma unroll
        for (int n = 0; n < 4; ++n) acc[m][n] = (f32x4){0.f, 0.f, 0.f, 0.f};

    int cSwz = ((lk ^ ((lr >> 1) & 3)) << 3);
    int aoff[4], boff[4];
#pragma unroll
    for (int m = 0; m < 4; ++m) aoff[m] = (wm * 64 + m * 16 + lr) * 32;
#pragma unroll
    for (int n = 0; n < 4; ++n) boff[n] = (wn * 64 + n * 16 + lr) * 32;

    G1_STAGE(0);
    G1_STAGE(1);

#pragma unroll 1
    for (int t3 = 0; t3 < 28; ++t3) {
        G2_STEP(0, 2, "vmcnt(3)", true);
        G2_STEP(1, 0, "vmcnt(3)", true);
        G2_STEP(2, 1, "vmcnt(3)", true);
    }
    G2_STEP(0, 2, "vmcnt(3)", false);
    G2_STEP(1, 0, "vmcnt(0)", false);

#pragma unroll
    for (int m = 0; m < 4; ++m) {
        int rl0 = wm * 64 + m * 16 + lk * 4;
#pragma unroll
        for (int q = 0; q < 4; ++q) {
            int rl = rl0 + q;
            if (r0 + rl < n_e) {
                float* orow = pout + (size_t)(p0 + rl) * DIMD + d0;
#pragma unroll
                for (int n = 0; n < 4; ++n) {
                    orow[wn * 64 + n * 16 + lr] = acc[m][n][q];
                }
            }
        }
    }
}

// ---------------- combine: out[t] = w0*pout[pos0] + w1*pout[pos1] -----------
__global__ void k_combine(const float4* __restrict__ pout, const int* __restrict__ pos,
                          const float* __restrict__ topw, float4* __restrict__ out) {
    int idx = blockIdx.x * 256 + threadIdx.x;
    int tok = idx >> 8, c = idx & 255;
    int p0 = pos[2 * tok], p1 = pos[2 * tok + 1];
    float w0 = topw[2 * tok], w1 = topw[2 * tok + 1];
    float4 a = pout[(size_t)p0 * 256 + c];
    float4 b = pout[(size_t)p1 * 256 + c];
    float4 r;
    r.x = w0 * a.x + w1 * b.x;
    r.y = w0 * a.y + w1 * b.y;
    r.z = w0 * a.z + w1 * b.z;
    r.w = w0 * a.w + w1 * b.w;
    out[idx] = r;
}

extern "C" void kernel_launch(void* const* d_in, const int* in_sizes, int n_in,
                              void* d_out, int out_size, void* d_ws, size_t ws_size,
                              hipStream_t stream) {
    const float* x   = (const float*)d_in[0];
    const float* wr  = (const float*)d_in[1];
    const float* w12 = (const float*)d_in[2];
    const float* w3  = (const float*)d_in[3];
    float* out = (float*)d_out;

    char* ws = (char*)d_ws;
    int*            ctrl = (int*)(ws + WS_CTRL);
    int*            topi = (int*)(ws + WS_TOPI);
    float*          topw = (float*)(ws + WS_TOPW);
    int*            pos  = (int*)(ws + WS_POS);
    int*            ptok = (int*)(ws + WS_PTOK);
    unsigned short* xb   = (unsigned short*)(ws + WS_XB);
    unsigned short* w12t = (unsigned short*)(ws + WS_W12T);
    unsigned short* w3t  = (unsigned short*)(ws + WS_W3T);
    unsigned short* hbuf = (unsigned short*)(ws + WS_HBUF);
    float*          pout = (float*)(ws + WS_POUT);

    (void)ws_size; (void)in_sizes; (void)n_in; (void)out_size;

    k_cvt_all<<<8320, 256, 0, stream>>>(w12, w3, w12t, w3t);
    k_router<<<2048, 256, 0, stream>>>((const float4*)x, wr, (ushort4*)xb, topi, topw);
    k_pack<<<1, 1024, 0, stream>>>(topi, ctrl, ptok, pos);
    k_gemm1<<<dim3(43, 32, 8), 512, 0, stream>>>(xb, w12t, ctrl, ptok, hbuf);
    k_gemm2<<<dim3(8, 32, 8), 512, 0, stream>>>(hbuf, w3t, ctrl, pout);
    k_combine<<<8192, 256, 0, stream>>>((const float4*)pout, pos, topw, (float4*)out);
}